// Round 4
// baseline (745.195 us; speedup 1.0000x reference)
//
#include <hip/hip_runtime.h>
#include <hip/hip_fp16.h>
#include <math.h>
#include <float.h>

// ---------------------------------------------------------------------------
// S_E epidemic step:
//   E' = relu(E-1); sus = (E==inf)*susceptiveness; infv = (E<=1)*infectiveness
//   acc[src] += log(1 - sus[src]*infv[dst])   over 32M edges (scatter-atomic)
//   out = (rand < 1-exp(acc)) ? incubation : E'
//
// R9: R6/R7/R8 all pinned at ~75-80G random-memory-transactions/s (MSHR-type
// ceiling: outstanding-miss slots / miss latency). Only levers: fewer random
// READS, or convert them to posted writes / LDS hits. R9 bins surviving edges
// by src bucket (4096 nodes):
//   K1 edge_bin: stream src/dst NT + LDS inf-bitmask test on dst (30% pass) +
//      append 4B records ((s&4095)<<20 | d) to per-(block,bucket) regions.
//      Random reads: ZERO. Binning = 9.6M posted 4B writes (cheap).
//   K2 bucket_process: block b stages sus slice (8KB) + f32 acc slice (16KB)
//      in LDS; reads its regions coalesced; only infv[dst] is a random read
//      (4.8M vs 19.2M before); accumulate via LDS atomics; flush slice with
//      plain RMW (exclusive ownership) -> no global atomics.
// Overflow/tails processed inline (correct for any distribution).
// Accumulation in log2 domain; final applies exp2f. acc lives in d_out.
// Epilogue scrubs non-finite bits.
// ---------------------------------------------------------------------------

typedef int v4i __attribute__((ext_vector_type(4)));

#define MAX_BIT_WORDS 32768   // u32 words -> 128 KiB LDS, supports n <= 1,048,576
#define NBLK1 256             // edge_bin grid size (fixed; bcounts layout)
#define BUCKET_SHIFT 12
#define BUCKET_SIZE 4096

__global__ void prep_full(const float* __restrict__ E,
                          const float* __restrict__ susc,
                          const float* __restrict__ infc,
                          __half* __restrict__ sus,
                          __half* __restrict__ infv,
                          unsigned long long* __restrict__ gbits, // may be null
                          float* __restrict__ acc,
                          int n) {
    int i = blockIdx.x * blockDim.x + threadIdx.x;
    float e = (i < n) ? E[i] : 2.0f;             // default: neither mask
    bool infective = (i < n) && (e <= 1.0f);
    unsigned long long m = __ballot(infective);  // wave64 ballot, all lanes
    if (i < n) {
        sus[i]  = __float2half(isinf(e) ? susc[i] : 0.0f);    // susceptible: E == inf
        infv[i] = __float2half(infective ? infc[i] : 0.0f);   // infective: E <= 1
        acc[i]  = 0.0f;
    }
    if (gbits && (threadIdx.x & 63) == 0 && i < n) {
        gbits[i >> 6] = m;                        // u32 word i>>5, bit i&31
    }
}

__global__ void prep_acc_only(float* __restrict__ acc, int n) {
    int i = blockIdx.x * blockDim.x + threadIdx.x;
    if (i < n) acc[i] = 0.0f;
}

// ---------------------------------------------------------------------------
// R9 K1: stream edges, LDS inf-bitmask filter on dst, bin survivors by src.
// Grid MUST be exactly NBLK1 blocks of 1024.
// ---------------------------------------------------------------------------
__global__ __launch_bounds__(1024, 4) void edge_bin(
        const int* __restrict__ src,
        const int* __restrict__ dst,
        const unsigned int* __restrict__ gbits,
        const unsigned short* __restrict__ susu,
        const unsigned short* __restrict__ infvu,
        float* __restrict__ acc,
        unsigned int* __restrict__ regions,   // [NBLK1][nbuck][rcap]
        unsigned int* __restrict__ bcounts,   // [NBLK1][nbuck]
        int n_edges, int nwords, int nbuck, int rcap) {
    __shared__ unsigned int bits[MAX_BIT_WORDS];
    __shared__ unsigned int bcnt[NBLK1];      // per-block bucket tails (nbuck<=256)
    for (int w = threadIdx.x; w < nwords; w += 1024)
        bits[w] = gbits[w];
    if (threadIdx.x < (unsigned)nbuck) bcnt[threadIdx.x] = 0;
    __syncthreads();

    const long long region_base = (long long)blockIdx.x * nbuck * rcap;

    long long nchunk = (long long)n_edges >> 3;        // 8 edges/chunk
    long long stride = (long long)gridDim.x * blockDim.x;
    for (long long c = (long long)blockIdx.x * blockDim.x + threadIdx.x;
         c < nchunk; c += stride) {
        v4i s0 = __builtin_nontemporal_load((const v4i*)src + 2 * c);
        v4i s1 = __builtin_nontemporal_load((const v4i*)src + 2 * c + 1);
        v4i d0 = __builtin_nontemporal_load((const v4i*)dst + 2 * c);
        v4i d1 = __builtin_nontemporal_load((const v4i*)dst + 2 * c + 1);
        int ss[8] = {s0.x, s0.y, s0.z, s0.w, s1.x, s1.y, s1.z, s1.w};
        int dd[8] = {d0.x, d0.y, d0.z, d0.w, d1.x, d1.y, d1.z, d1.w};
#pragma unroll
        for (int k = 0; k < 8; ++k) {
            int d = dd[k];
            if ((bits[d >> 5] >> (d & 31)) & 1u) {     // dst infective (~30%)
                int s = ss[k];
                int b = s >> BUCKET_SHIFT;
                unsigned rec = ((unsigned)(s & (BUCKET_SIZE - 1)) << 20) | (unsigned)d;
                unsigned pos = atomicAdd(&bcnt[b], 1u);         // LDS atomic
                if (pos < (unsigned)rcap) {
                    __builtin_nontemporal_store(rec,
                        regions + region_base + (long long)b * rcap + pos);
                } else {
                    // overflow safety net (statistically never): inline process
                    unsigned short svu = susu[s];
                    if (svu) {
                        float sv = __half2float(__ushort_as_half(svu));
                        float iv = __half2float(__ushort_as_half(infvu[d]));
                        float p = sv * iv;
                        if (p != 0.0f) atomicAdd(&acc[s], __log2f(1.0f - p));
                    }
                }
            }
        }
    }

    __syncthreads();
    if (threadIdx.x < (unsigned)nbuck) {
        bcounts[blockIdx.x * nbuck + threadIdx.x] = bcnt[threadIdx.x];
    }

    // tail (n_edges % 8): inline, block 0
    long long tb = nchunk << 3;
    int tail = (int)(n_edges - tb);
    if (blockIdx.x == 0 && (int)threadIdx.x < tail) {
        long long e = tb + threadIdx.x;
        int d = dst[e];
        if ((bits[d >> 5] >> (d & 31)) & 1u) {
            int s = src[e];
            unsigned short svu = susu[s];
            if (svu) {
                float sv = __half2float(__ushort_as_half(svu));
                float iv = __half2float(__ushort_as_half(infvu[d]));
                float p = sv * iv;
                if (p != 0.0f) atomicAdd(&acc[s], __log2f(1.0f - p));
            }
        }
    }
}

// ---------------------------------------------------------------------------
// R9 K2: one block per src bucket. sus slice + f32 acc slice in LDS; only
// infv[dst] is a random global read; flush slice with plain RMW.
// ---------------------------------------------------------------------------
__global__ __launch_bounds__(1024, 4) void bucket_process(
        const unsigned int* __restrict__ regions,
        const unsigned int* __restrict__ bcounts,
        const unsigned short* __restrict__ susu,
        const unsigned short* __restrict__ infvu,
        float* __restrict__ acc,
        int n, int nbuck, int rcap) {
    __shared__ unsigned short lsus[BUCKET_SIZE];
    __shared__ float laccs[BUCKET_SIZE];

    const int b = blockIdx.x;
    const int base_node = b << BUCKET_SHIFT;

    for (int i = threadIdx.x; i < BUCKET_SIZE; i += blockDim.x) {
        int g = base_node + i;
        lsus[i]  = (g < n) ? susu[g] : (unsigned short)0;
        laccs[i] = 0.0f;
    }
    __syncthreads();

    const int wid  = threadIdx.x >> 6;
    const int lane = threadIdx.x & 63;
    const int nw   = blockDim.x >> 6;   // 16 waves

    // waves process different source-blocks' regions concurrently
    for (int blk = wid; blk < NBLK1; blk += nw) {
        unsigned cnt = bcounts[blk * nbuck + b];
        if (cnt > (unsigned)rcap) cnt = (unsigned)rcap;
        const long long rb = ((long long)blk * nbuck + b) * (long long)rcap;
        for (unsigned i = lane; i < cnt; i += 64) {
            unsigned rec = __builtin_nontemporal_load(regions + rb + i);
            int sl = (int)(rec >> 20);
            int d  = (int)(rec & 0xFFFFFu);
            unsigned short svu = lsus[sl];
            // masked full-exec gather: failing lanes hit line 0
            unsigned short ivu = infvu[svu ? d : 0];
            float p = __half2float(__ushort_as_half(svu)) *
                      __half2float(__ushort_as_half(ivu));
            if (p != 0.0f)
                atomicAdd(&laccs[sl], __log2f(1.0f - p));   // LDS atomic
        }
    }
    __syncthreads();

    // flush: exclusive ownership of [base_node, base_node+4096) -> plain RMW
    for (int i = threadIdx.x; i < BUCKET_SIZE; i += blockDim.x) {
        int g = base_node + i;
        if (g < n) {
            float v = laccs[i];
            if (v != 0.0f) acc[g] += v;   // preserves K1 inline-overflow adds
        }
    }
}

// ---------------------------------------------------------------------------
// Fallback (proven R6 path): LDS bitmask, divergent 8-edge loop. ~262 us.
// ---------------------------------------------------------------------------
__global__ __launch_bounds__(1024, 4) void edge_lds(
        const int* __restrict__ src,
        const int* __restrict__ dst,
        const __half* __restrict__ sus,
        const __half* __restrict__ infv,
        const unsigned int* __restrict__ gbits,
        float* __restrict__ acc,
        int n_edges, int nwords) {
    __shared__ unsigned int bits[MAX_BIT_WORDS];
    for (int w = threadIdx.x; w < nwords; w += 1024)
        bits[w] = gbits[w];
    __syncthreads();

    const unsigned short* susu  = (const unsigned short*)sus;
    const unsigned short* infvu = (const unsigned short*)infv;

    long long nchunk = (long long)n_edges >> 3;
    long long stride = (long long)gridDim.x * blockDim.x;
    for (long long c = (long long)blockIdx.x * blockDim.x + threadIdx.x;
         c < nchunk; c += stride) {
        v4i s0 = __builtin_nontemporal_load((const v4i*)src + 2 * c);
        v4i s1 = __builtin_nontemporal_load((const v4i*)src + 2 * c + 1);
        v4i d0 = __builtin_nontemporal_load((const v4i*)dst + 2 * c);
        v4i d1 = __builtin_nontemporal_load((const v4i*)dst + 2 * c + 1);
        int ss[8] = {s0.x, s0.y, s0.z, s0.w, s1.x, s1.y, s1.z, s1.w};
        int dd[8] = {d0.x, d0.y, d0.z, d0.w, d1.x, d1.y, d1.z, d1.w};
#pragma unroll
        for (int k = 0; k < 8; ++k) {
            int d = dd[k];
            if ((bits[d >> 5] >> (d & 31)) & 1u) {
                int s = ss[k];
                unsigned short svu = susu[s];
                if (svu) {
                    float sv = __half2float(__ushort_as_half(svu));
                    float iv = __half2float(__ushort_as_half(infvu[d]));
                    float p = sv * iv;
                    if (p != 0.0f)
                        atomicAdd(&acc[s], __log2f(1.0f - p));
                }
            }
        }
    }

    long long tb = nchunk << 3;
    int tail = (int)(n_edges - tb);
    if (blockIdx.x == 0 && (int)threadIdx.x < tail) {
        long long e = tb + threadIdx.x;
        int d = dst[e];
        if ((bits[d >> 5] >> (d & 31)) & 1u) {
            int s = src[e];
            unsigned short svu = susu[s];
            if (svu) {
                float sv = __half2float(__ushort_as_half(svu));
                float iv = __half2float(__ushort_as_half(infvu[d]));
                float p = sv * iv;
                if (p != 0.0f)
                    atomicAdd(&acc[s], __log2f(1.0f - p));
            }
        }
    }
}

// ---------------------------------------------------------------------------
// Fallback A (n too big for LDS bitmask): R5 structure, log2 domain.
// ---------------------------------------------------------------------------
__global__ void edge_fast(const int* __restrict__ src,
                          const int* __restrict__ dst,
                          const __half* __restrict__ sus,
                          const __half* __restrict__ infv,
                          float* __restrict__ acc,
                          int n_edges) {
    int t = blockIdx.x * blockDim.x + threadIdx.x;
    long long base = (long long)t * 4;
    if (base + 3 < n_edges) {
        v4i s4 = __builtin_nontemporal_load((const v4i*)src + t);
        v4i d4 = __builtin_nontemporal_load((const v4i*)dst + t);
        int ss[4] = {s4.x, s4.y, s4.z, s4.w};
        int dd[4] = {d4.x, d4.y, d4.z, d4.w};
#pragma unroll
        for (int k = 0; k < 4; ++k) {
            float sv = __half2float(sus[ss[k]]);
            if (sv != 0.0f) {
                float iv = __half2float(infv[dd[k]]);
                if (iv != 0.0f) {
                    atomicAdd(&acc[ss[k]], __log2f(1.0f - sv * iv));
                }
            }
        }
    } else if (base < n_edges) {
        for (long long e = base; e < n_edges; ++e) {
            int s = src[e];
            float sv = __half2float(sus[s]);
            if (sv != 0.0f) {
                float iv = __half2float(infv[dst[e]]);
                if (iv != 0.0f) atomicAdd(&acc[s], __log2f(1.0f - sv * iv));
            }
        }
    }
}

// ---------------------------------------------------------------------------
// Fallback B (ws too small): recompute masks inline per edge, log2 domain.
// ---------------------------------------------------------------------------
__global__ void edge_inline(const int* __restrict__ src,
                            const int* __restrict__ dst,
                            const float* __restrict__ E,
                            const float* __restrict__ susc,
                            const float* __restrict__ infc,
                            float* __restrict__ acc,
                            int n_edges) {
    long long e = (long long)blockIdx.x * blockDim.x + threadIdx.x;
    if (e < n_edges) {
        int s = src[e];
        if (isinf(E[s])) {
            int d = dst[e];
            if (E[d] <= 1.0f) {
                atomicAdd(&acc[s], __log2f(1.0f - susc[s] * infc[d]));
            }
        }
    }
}

__global__ void final_kernel(const float* __restrict__ E,
                             const float* __restrict__ rnd,
                             const float* __restrict__ incub,
                             float* __restrict__ out,  // also holds acc (log2 domain)
                             int n) {
    int i = blockIdx.x * blockDim.x + threadIdx.x;
    if (i < n) {
        float a = out[i];                           // acc (in-place), sum of log2 terms
        float e_new = fmaxf(E[i] - 1.0f, 0.0f);     // relu(E-1)
        float p = 1.0f - exp2f(a);
        float r = (rnd[i] < p) ? incub[i] : e_new;
        // scrub non-finite (inf/nan) at the bit level
        unsigned bits = __float_as_uint(r);
        if ((bits & 0x7f800000u) == 0x7f800000u) r = 3.0e38f;
        out[i] = r;
    }
}

extern "C" void kernel_launch(void* const* d_in, const int* in_sizes, int n_in,
                              void* d_out, int out_size, void* d_ws, size_t ws_size,
                              hipStream_t stream) {
    const float* E     = (const float*)d_in[0];
    const float* susc  = (const float*)d_in[1];
    const float* infc  = (const float*)d_in[2];
    const float* incub = (const float*)d_in[3];
    const float* rnd   = (const float*)d_in[4];
    const int*   src   = (const int*)d_in[5];
    const int*   dst   = (const int*)d_in[6];
    int n       = in_sizes[0];
    int n_edges = in_sizes[5];

    float* acc = (float*)d_out;  // acc lives in the output buffer

    const int B = 256;
    int nb_nodes = (n + B - 1) / B;

    int nwords64 = (n + 63) / 64;               // ull words of bitmask
    int nwords32 = (n + 31) / 32;               // u32 words of bitmask
    int nbuck    = (n + BUCKET_SIZE - 1) >> BUCKET_SHIFT;   // <= 256 when n <= 1M

    size_t tables_bytes = (size_t)4 * n;        // sus + infv fp16
    size_t bits_off     = (tables_bytes + 7) & ~(size_t)7;
    size_t bcounts_off  = bits_off + (size_t)nwords64 * 8;
    size_t regions_off  = (bcounts_off + (size_t)NBLK1 * nbuck * 4 + 15) & ~(size_t)15;

    // adaptive region capacity per (block, bucket)
    long long rcap = 0;
    if (ws_size > regions_off) {
        size_t avail = ws_size - regions_off;
        rcap = (long long)(avail / ((size_t)NBLK1 * (size_t)nbuck * 4));
        if (rcap > 512) rcap = 512;
    }

    size_t need_r6 = bcounts_off;               // tables + bits (R6 path)

    if (nwords32 <= MAX_BIT_WORDS && nbuck <= NBLK1 && rcap >= 224) {
        // R9 path: bin by src bucket, process with LDS slices
        __half* sus  = (__half*)d_ws;
        __half* infv = sus + n;
        unsigned long long* gbits = (unsigned long long*)((char*)d_ws + bits_off);
        unsigned int* bcounts = (unsigned int*)((char*)d_ws + bcounts_off);
        unsigned int* regions = (unsigned int*)((char*)d_ws + regions_off);

        prep_full<<<nb_nodes, B, 0, stream>>>(E, susc, infc, sus, infv, gbits, acc, n);
        edge_bin<<<NBLK1, 1024, 0, stream>>>(src, dst, (const unsigned int*)gbits,
                                             (const unsigned short*)sus,
                                             (const unsigned short*)infv,
                                             acc, regions, bcounts,
                                             n_edges, nwords32, nbuck, (int)rcap);
        bucket_process<<<nbuck, 1024, 0, stream>>>(regions, bcounts,
                                                   (const unsigned short*)sus,
                                                   (const unsigned short*)infv,
                                                   acc, n, nbuck, (int)rcap);
    } else if (ws_size >= need_r6 && nwords32 <= MAX_BIT_WORDS) {
        // R6 path: fp16 tables + bitmask, LDS-filtered divergent edges
        __half* sus  = (__half*)d_ws;
        __half* infv = sus + n;
        unsigned long long* gbits = (unsigned long long*)((char*)d_ws + bits_off);
        prep_full<<<nb_nodes, B, 0, stream>>>(E, susc, infc, sus, infv, gbits, acc, n);
        edge_lds<<<256, 1024, 0, stream>>>(src, dst, sus, infv,
                                           (const unsigned int*)gbits, acc,
                                           n_edges, nwords32);
    } else if (ws_size >= tables_bytes) {
        // Fallback A: fp16 tables, no bitmask
        __half* sus  = (__half*)d_ws;
        __half* infv = sus + n;
        prep_full<<<nb_nodes, B, 0, stream>>>(E, susc, infc, sus, infv, nullptr, acc, n);
        int n_vec = (n_edges + 3) / 4;
        edge_fast<<<(n_vec + B - 1) / B, B, 0, stream>>>(src, dst, sus, infv, acc, n_edges);
    } else {
        // Fallback B: tiny ws
        prep_acc_only<<<nb_nodes, B, 0, stream>>>(acc, n);
        long long nb_e = ((long long)n_edges + B - 1) / B;
        edge_inline<<<(unsigned)nb_e, B, 0, stream>>>(src, dst, E, susc, infc, acc, n_edges);
    }

    final_kernel<<<nb_nodes, B, 0, stream>>>(E, rnd, incub, acc, n);
}

// Round 6
// 487.055 us; speedup vs baseline: 1.5300x; 1.5300x over previous
//
#include <hip/hip_runtime.h>
#include <hip/hip_fp16.h>
#include <math.h>
#include <float.h>

// ---------------------------------------------------------------------------
// S_E epidemic step:
//   E' = relu(E-1); sus = (E==inf)*susceptiveness; infv = (E<=1)*infectiveness
//   acc[src] += log(1 - sus[src]*infv[dst])   over 32M edges (scatter-atomic)
//   out = (rand < 1-exp(acc)) ? incubation : E'
//
// R11 = R6 configuration (best measured: 489 us total, edge_lds 262 us).
// Session findings (R6-R9): the edge phase is pinned at ~75-80 G random-
// transactions/s (per-CU MSHR x L2 latency; occupancy-independent).
//   R6: 19.2M transactions (9.6M sus gather + 4.8M infv gather + 4.8M atomic)
//       -> 262 us = 73G/s, ~8% off the 240 us floor for that count.
//   R7 (in-loop masked phases): codegen re-serialized, VGPR 64, occ 33%. -28us.
//   R8 (filter+compact / dense process): same transaction bill + 85us filter.
//   R9 (src-bucket binning): scattered 4B writes pay the SAME ceiling with
//       2.2x RMW write amplification + LDS-atomic conflicts. -200us.
// No ordering of this algorithm's required transactions goes below ~19.2M
// without adding stream passes that cost more (dual-endpoint LDS filter
// needs 244KB > 160KB LDS; coarse sus mask useless at 50% density).
// R6 is the optimum found.
//
// Structure: LDS-resident infective bitmask (1 bit/node, 122KB) filters 70%
// of edges with a ds_read; fp16 sus/infv tables (2MB each, L2-resident)
// serve the surviving gathers; accumulation in log2 domain (hw v_log_f32);
// final applies exp2f. acc lives in d_out. Epilogue scrubs non-finite bits.
// ---------------------------------------------------------------------------

typedef int v4i __attribute__((ext_vector_type(4)));

#define MAX_BIT_WORDS 32768   // u32 words -> 128 KiB LDS, supports n <= 1,048,576

__global__ void prep_full(const float* __restrict__ E,
                          const float* __restrict__ susc,
                          const float* __restrict__ infc,
                          __half* __restrict__ sus,
                          __half* __restrict__ infv,
                          unsigned long long* __restrict__ gbits, // may be null
                          float* __restrict__ acc,
                          int n) {
    int i = blockIdx.x * blockDim.x + threadIdx.x;
    float e = (i < n) ? E[i] : 2.0f;             // default: neither mask
    bool infective = (i < n) && (e <= 1.0f);
    unsigned long long m = __ballot(infective);  // wave64 ballot, all lanes
    if (i < n) {
        sus[i]  = __float2half(isinf(e) ? susc[i] : 0.0f);    // susceptible: E == inf
        infv[i] = __float2half(infective ? infc[i] : 0.0f);   // infective: E <= 1
        acc[i]  = 0.0f;
    }
    if (gbits && (threadIdx.x & 63) == 0 && i < n) {
        gbits[i >> 6] = m;                        // u32 word i>>5, bit i&31
    }
}

__global__ void prep_acc_only(float* __restrict__ acc, int n) {
    int i = blockIdx.x * blockDim.x + threadIdx.x;
    if (i < n) acc[i] = 0.0f;
}

// ---------------------------------------------------------------------------
// Main edge kernel (R6): LDS bitmask filter, divergent 8-edge inner loop.
// Measured: 262 us, VGPR 52, occupancy 44%, 73G random transactions/s.
// ---------------------------------------------------------------------------
__global__ __launch_bounds__(1024, 4) void edge_lds(
        const int* __restrict__ src,
        const int* __restrict__ dst,
        const __half* __restrict__ sus,
        const __half* __restrict__ infv,
        const unsigned int* __restrict__ gbits,
        float* __restrict__ acc,
        int n_edges, int nwords) {
    __shared__ unsigned int bits[MAX_BIT_WORDS];
    for (int w = threadIdx.x; w < nwords; w += 1024)
        bits[w] = gbits[w];
    __syncthreads();

    const unsigned short* susu  = (const unsigned short*)sus;
    const unsigned short* infvu = (const unsigned short*)infv;

    long long nchunk = (long long)n_edges >> 3;
    long long stride = (long long)gridDim.x * blockDim.x;
    for (long long c = (long long)blockIdx.x * blockDim.x + threadIdx.x;
         c < nchunk; c += stride) {
        v4i s0 = __builtin_nontemporal_load((const v4i*)src + 2 * c);
        v4i s1 = __builtin_nontemporal_load((const v4i*)src + 2 * c + 1);
        v4i d0 = __builtin_nontemporal_load((const v4i*)dst + 2 * c);
        v4i d1 = __builtin_nontemporal_load((const v4i*)dst + 2 * c + 1);
        int ss[8] = {s0.x, s0.y, s0.z, s0.w, s1.x, s1.y, s1.z, s1.w};
        int dd[8] = {d0.x, d0.y, d0.z, d0.w, d1.x, d1.y, d1.z, d1.w};
#pragma unroll
        for (int k = 0; k < 8; ++k) {
            int d = dd[k];
            if ((bits[d >> 5] >> (d & 31)) & 1u) {        // ~30% pass (LDS)
                int s = ss[k];
                unsigned short svu = susu[s];             // fp16 gather (L2-hot)
                if (svu) {                                // ~50% pass
                    float sv = __half2float(__ushort_as_half(svu));
                    float iv = __half2float(__ushort_as_half(infvu[d]));
                    float p = sv * iv;
                    if (p != 0.0f)
                        atomicAdd(&acc[s], __log2f(1.0f - p));
                }
            }
        }
    }

    // tail (n_edges % 8)
    long long tb = nchunk << 3;
    int tail = (int)(n_edges - tb);
    if (blockIdx.x == 0 && (int)threadIdx.x < tail) {
        long long e = tb + threadIdx.x;
        int d = dst[e];
        if ((bits[d >> 5] >> (d & 31)) & 1u) {
            int s = src[e];
            unsigned short svu = susu[s];
            if (svu) {
                float sv = __half2float(__ushort_as_half(svu));
                float iv = __half2float(__ushort_as_half(infvu[d]));
                float p = sv * iv;
                if (p != 0.0f)
                    atomicAdd(&acc[s], __log2f(1.0f - p));
            }
        }
    }
}

// ---------------------------------------------------------------------------
// Fallback A (n too big for LDS bitmask): R5 structure, log2 domain.
// ---------------------------------------------------------------------------
__global__ void edge_fast(const int* __restrict__ src,
                          const int* __restrict__ dst,
                          const __half* __restrict__ sus,
                          const __half* __restrict__ infv,
                          float* __restrict__ acc,
                          int n_edges) {
    int t = blockIdx.x * blockDim.x + threadIdx.x;
    long long base = (long long)t * 4;
    if (base + 3 < n_edges) {
        v4i s4 = __builtin_nontemporal_load((const v4i*)src + t);
        v4i d4 = __builtin_nontemporal_load((const v4i*)dst + t);
        int ss[4] = {s4.x, s4.y, s4.z, s4.w};
        int dd[4] = {d4.x, d4.y, d4.z, d4.w};
#pragma unroll
        for (int k = 0; k < 4; ++k) {
            float sv = __half2float(sus[ss[k]]);
            if (sv != 0.0f) {
                float iv = __half2float(infv[dd[k]]);
                if (iv != 0.0f) {
                    atomicAdd(&acc[ss[k]], __log2f(1.0f - sv * iv));
                }
            }
        }
    } else if (base < n_edges) {
        for (long long e = base; e < n_edges; ++e) {
            int s = src[e];
            float sv = __half2float(sus[s]);
            if (sv != 0.0f) {
                float iv = __half2float(infv[dst[e]]);
                if (iv != 0.0f) atomicAdd(&acc[s], __log2f(1.0f - sv * iv));
            }
        }
    }
}

// ---------------------------------------------------------------------------
// Fallback B (ws too small): recompute masks inline per edge, log2 domain.
// ---------------------------------------------------------------------------
__global__ void edge_inline(const int* __restrict__ src,
                            const int* __restrict__ dst,
                            const float* __restrict__ E,
                            const float* __restrict__ susc,
                            const float* __restrict__ infc,
                            float* __restrict__ acc,
                            int n_edges) {
    long long e = (long long)blockIdx.x * blockDim.x + threadIdx.x;
    if (e < n_edges) {
        int s = src[e];
        if (isinf(E[s])) {
            int d = dst[e];
            if (E[d] <= 1.0f) {
                atomicAdd(&acc[s], __log2f(1.0f - susc[s] * infc[d]));
            }
        }
    }
}

__global__ void final_kernel(const float* __restrict__ E,
                             const float* __restrict__ rnd,
                             const float* __restrict__ incub,
                             float* __restrict__ out,  // also holds acc (log2 domain)
                             int n) {
    int i = blockIdx.x * blockDim.x + threadIdx.x;
    if (i < n) {
        float a = out[i];                           // acc (in-place), sum of log2 terms
        float e_new = fmaxf(E[i] - 1.0f, 0.0f);     // relu(E-1)
        float p = 1.0f - exp2f(a);
        float r = (rnd[i] < p) ? incub[i] : e_new;
        // scrub non-finite (inf/nan) at the bit level
        unsigned bits = __float_as_uint(r);
        if ((bits & 0x7f800000u) == 0x7f800000u) r = 3.0e38f;
        out[i] = r;
    }
}

extern "C" void kernel_launch(void* const* d_in, const int* in_sizes, int n_in,
                              void* d_out, int out_size, void* d_ws, size_t ws_size,
                              hipStream_t stream) {
    const float* E     = (const float*)d_in[0];
    const float* susc  = (const float*)d_in[1];
    const float* infc  = (const float*)d_in[2];
    const float* incub = (const float*)d_in[3];
    const float* rnd   = (const float*)d_in[4];
    const int*   src   = (const int*)d_in[5];
    const int*   dst   = (const int*)d_in[6];
    int n       = in_sizes[0];
    int n_edges = in_sizes[5];

    float* acc = (float*)d_out;  // acc lives in the output buffer

    const int B = 256;
    int nb_nodes = (n + B - 1) / B;

    int nwords64 = (n + 63) / 64;               // ull words of bitmask
    int nwords32 = (n + 31) / 32;               // u32 words of bitmask
    size_t tables_bytes = (size_t)4 * n;        // sus + infv fp16
    size_t bits_off     = (tables_bytes + 7) & ~(size_t)7;
    size_t need_lds     = bits_off + (size_t)nwords64 * 8;

    if (ws_size >= need_lds && nwords32 <= MAX_BIT_WORDS) {
        // R6 path: fp16 tables + global bitmask staging, LDS-filtered edges
        __half* sus  = (__half*)d_ws;
        __half* infv = sus + n;
        unsigned long long* gbits = (unsigned long long*)((char*)d_ws + bits_off);
        prep_full<<<nb_nodes, B, 0, stream>>>(E, susc, infc, sus, infv, gbits, acc, n);
        edge_lds<<<256, 1024, 0, stream>>>(src, dst, sus, infv,
                                           (const unsigned int*)gbits, acc,
                                           n_edges, nwords32);
    } else if (ws_size >= tables_bytes) {
        // Fallback A: fp16 tables, no bitmask
        __half* sus  = (__half*)d_ws;
        __half* infv = sus + n;
        prep_full<<<nb_nodes, B, 0, stream>>>(E, susc, infc, sus, infv, nullptr, acc, n);
        int n_vec = (n_edges + 3) / 4;
        edge_fast<<<(n_vec + B - 1) / B, B, 0, stream>>>(src, dst, sus, infv, acc, n_edges);
    } else {
        // Fallback B: tiny ws
        prep_acc_only<<<nb_nodes, B, 0, stream>>>(acc, n);
        long long nb_e = ((long long)n_edges + B - 1) / B;
        edge_inline<<<(unsigned)nb_e, B, 0, stream>>>(src, dst, E, susc, infc, acc, n_edges);
    }

    final_kernel<<<nb_nodes, B, 0, stream>>>(E, rnd, incub, acc, n);
}